// Round 9
// baseline (202.903 us; speedup 1.0000x reference)
//
#include <hip/hip_runtime.h>
#include <hip/hip_bf16.h>
#include <math.h>

#define T_ 8
#define N_ 2048
#define F_ 128
#define H_ 4
#define NT_ (N_ / 32)   // 64 key tiles per (h,t)

typedef unsigned int u32;
typedef unsigned short ushort_t;
typedef float f32x16 __attribute__((ext_vector_type(16)));
typedef _Float16 f16x8 __attribute__((ext_vector_type(8)));
typedef u32 u32x4 __attribute__((ext_vector_type(4)));

// ---------------------------------------------------------------------------
// Kernel 1: th = x @ W per (h,t) in fp32; writes fp16 hi and the transposed
// copy th_hiT[ht][n/32][g][32] with the inner m-index PERMUTED (bit2<->bit3)
// so PV's B-fragment needs no cross-lane shuffles (k-permutation trick).
// (unchanged from R8)
// ---------------------------------------------------------------------------
__global__ __launch_bounds__(256) void k_th(const float* __restrict__ x,
                                            const float* __restrict__ W,
                                            ushort_t* __restrict__ th_hi,
                                            ushort_t* __restrict__ th_hiT) {
    __shared__ float xs[64][132];

    const int b = blockIdx.x;
    const int h = b / (T_ * (N_ / 64));
    const int rem = b % (T_ * (N_ / 64));
    const int t = rem / (N_ / 64);
    const int n0 = (rem % (N_ / 64)) * 64;
    const int tid = threadIdx.x;

    {
        const int r = tid >> 2;
        const int c0 = (tid & 3) * 32;
        const float4* src = reinterpret_cast<const float4*>(
            x + ((size_t)t * N_ + (n0 + r)) * F_ + c0);
        #pragma unroll
        for (int u = 0; u < 8; ++u) {
            float4 v = src[u];
            int c = c0 + u * 4;
            xs[r][c + 0] = v.x; xs[r][c + 1] = v.y;
            xs[r][c + 2] = v.z; xs[r][c + 3] = v.w;
        }
    }
    __syncthreads();

    const int rowg = tid >> 4;
    const int colg = tid & 15;
    const int r0 = rowg * 4;
    const int c0 = colg * 8;

    float acc[4][8];
    #pragma unroll
    for (int i = 0; i < 4; ++i)
        #pragma unroll
        for (int j = 0; j < 8; ++j) acc[i][j] = 0.f;

    const float* Wb = W + (size_t)h * F_ * F_ + c0;
    #pragma unroll 4
    for (int f = 0; f < F_; ++f) {
        const float4 w0 = *reinterpret_cast<const float4*>(Wb + (size_t)f * F_);
        const float4 w1 = *reinterpret_cast<const float4*>(Wb + (size_t)f * F_ + 4);
        float a[4];
        #pragma unroll
        for (int i = 0; i < 4; ++i) a[i] = xs[r0 + i][f];
        #pragma unroll
        for (int i = 0; i < 4; ++i) {
            acc[i][0] += a[i] * w0.x; acc[i][1] += a[i] * w0.y;
            acc[i][2] += a[i] * w0.z; acc[i][3] += a[i] * w0.w;
            acc[i][4] += a[i] * w1.x; acc[i][5] += a[i] * w1.y;
            acc[i][6] += a[i] * w1.z; acc[i][7] += a[i] * w1.w;
        }
    }

    ushort_t hiv[4][8];
    #pragma unroll
    for (int i = 0; i < 4; ++i)
        #pragma unroll
        for (int j = 0; j < 8; ++j) {
            _Float16 hh = (_Float16)acc[i][j];   // RTN
            hiv[i][j] = __builtin_bit_cast(ushort_t, hh);
        }

    const size_t rowbase = (((size_t)h * T_ + t) * N_ + n0);
    #pragma unroll
    for (int i = 0; i < 4; ++i) {
        uint4 hv = *reinterpret_cast<uint4*>(&hiv[i][0]);
        *reinterpret_cast<uint4*>(th_hi + (rowbase + r0 + i) * F_ + c0) = hv;
    }

    // transposed chunked copy: [h][t][nc][g][32], inner m-index bit2<->bit3
    {
        const int nc = (n0 + r0) >> 5;
        const int nin = r0 & 31;                 // multiple of 4
        const int npin = (nin & 0x10) | ((nin & 4) << 1) | ((nin & 8) >> 1);
        ushort_t* base = th_hiT + ((((size_t)h * T_ + t) * (N_ / 32) + nc) * F_) * 32;
        #pragma unroll
        for (int j = 0; j < 8; ++j) {
            u32 p0 = (u32)hiv[0][j] | ((u32)hiv[1][j] << 16);
            u32 p1 = (u32)hiv[2][j] | ((u32)hiv[3][j] << 16);
            u32* dst = reinterpret_cast<u32*>(base + (size_t)(c0 + j) * 32 + npin);
            dst[0] = p0;
            dst[1] = p1;
        }
    }
}

// ---------------------------------------------------------------------------
// Kernel 2: MFMA flash attention, S^T = K*Q^T, single-term fp16 scores.
// R9: 64 q-columns per WAVE (two 32-q groups) -> every K/V LDS fragment read
// feeds 2 MFMAs; DS reads per q halved. Block = 128 thr (2 waves), grid 512,
// 2 blk/CU, 1 wave/SIMD, ~330 VGPR. fp16 s_part output.
// ---------------------------------------------------------------------------
__global__ __launch_bounds__(128, 1) void k_attn(const ushort_t* __restrict__ th_hi,
                                                 const ushort_t* __restrict__ th_hiT,
                                                 ushort_t* __restrict__ s_part) {
    __shared__ ushort_t kh[3][32][128];
    __shared__ ushort_t vt[3][64][72];

    const int tid = threadIdx.x;      // 0..127
    const int lane = tid & 63;
    const int w = tid >> 6;           // wave 0..1
    const int l31 = lane & 31;
    const int h5 = lane >> 5;

    // XCD-grouping swizzle (proven: FETCH ~17MB): 64 vids per XCD
    const int vid = ((blockIdx.x & 7) << 6) | (blockIdx.x >> 3);
    const int h = vid >> 7;
    const int t = (vid >> 4) & 7;
    const int qt = vid & 15;
    const int q0 = qt * 128 + w * 64;     // wave covers q0..q0+63

    const size_t ht = (size_t)h * T_ + t;
    const ushort_t* Khi_g = th_hi + ht * (N_ * F_);
    const ushort_t* VT_g  = th_hiT + ht * ((N_ / 32) * F_ * 32);
    const ushort_t* Qhi_g = th_hi + ((size_t)h * T_ + (T_ - 1)) * (N_ * F_);

    // Q fragments for the two 32-col groups: q = q0 + gq*32 + l31
    f16x8 qhA[8], qhB[8];
    {
        const ushort_t* qrA = Qhi_g + (size_t)(q0 + l31) * F_ + h5 * 8;
        const ushort_t* qrB = Qhi_g + (size_t)(q0 + 32 + l31) * F_ + h5 * 8;
        #pragma unroll
        for (int ks = 0; ks < 8; ++ks) {
            qhA[ks] = *reinterpret_cast<const f16x8*>(qrA + ks * 16);
            qhB[ks] = *reinterpret_cast<const f16x8*>(qrB + ks * 16);
        }
    }

    // staging maps (128 threads)
    const int sm = tid >> 2;            // K row 0..31
    const int sfc = tid & 3;            // K 32-elem f block
    const int ssx = sm & 15;
    // V: thread covers th_hiT g-row = tid (32 m-entries = 4 uint4)

    f32x16 o2A[4], o2B[4];
    #pragma unroll
    for (int gs = 0; gs < 4; ++gs)
        #pragma unroll
        for (int r = 0; r < 16; ++r) { o2A[gs][r] = 0.f; o2B[gs][r] = 0.f; }

    float mA_run = -3e38f, lA_run = 0.f;   // per-half-wave partials
    float mB_run = -3e38f, lB_run = 0.f;
    const float CL2 = 1.4426950408889634f;

    uint4 sa0, sa1, sa2, sa3, sv0, sv1, sv2, sv3;   // T14 staging registers

    auto stage_load = [&](int mt) {
        const size_t grow = (size_t)(mt * 32 + sm) * F_ + sfc * 32;
        sa0 = *reinterpret_cast<const uint4*>(Khi_g + grow);
        sa1 = *reinterpret_cast<const uint4*>(Khi_g + grow + 8);
        sa2 = *reinterpret_cast<const uint4*>(Khi_g + grow + 16);
        sa3 = *reinterpret_cast<const uint4*>(Khi_g + grow + 24);
        const ushort_t* vsrc = VT_g + (size_t)mt * (F_ * 32) + (size_t)tid * 32;
        sv0 = *reinterpret_cast<const uint4*>(vsrc);
        sv1 = *reinterpret_cast<const uint4*>(vsrc + 8);
        sv2 = *reinterpret_cast<const uint4*>(vsrc + 16);
        sv3 = *reinterpret_cast<const uint4*>(vsrc + 24);
    };
    auto stage_write = [&](int buf) {
        *reinterpret_cast<uint4*>(&kh[buf][sm][((sfc * 4 + 0) ^ ssx) * 8]) = sa0;
        *reinterpret_cast<uint4*>(&kh[buf][sm][((sfc * 4 + 1) ^ ssx) * 8]) = sa1;
        *reinterpret_cast<uint4*>(&kh[buf][sm][((sfc * 4 + 2) ^ ssx) * 8]) = sa2;
        *reinterpret_cast<uint4*>(&kh[buf][sm][((sfc * 4 + 3) ^ ssx) * 8]) = sa3;
        ushort_t* vdst = &vt[buf][tid >> 1][(tid & 1) * 32];
        *reinterpret_cast<uint4*>(vdst) = sv0;
        *reinterpret_cast<uint4*>(vdst + 8) = sv1;
        *reinterpret_cast<uint4*>(vdst + 16) = sv2;
        *reinterpret_cast<uint4*>(vdst + 24) = sv3;
    };
    auto scores = [&](int buf, f32x16& S0, f32x16& S1) {
        #pragma unroll
        for (int r = 0; r < 16; ++r) { S0[r] = 0.f; S1[r] = 0.f; }
        __builtin_amdgcn_s_setprio(1);
        #pragma unroll
        for (int ks = 0; ks < 8; ++ks) {
            const f16x8 ah = *reinterpret_cast<const f16x8*>(
                &kh[buf][l31][((ks * 2 + h5) ^ (l31 & 15)) * 8]);
            S0 = __builtin_amdgcn_mfma_f32_32x32x16_f16(ah, qhA[ks], S0, 0, 0, 0);
            S1 = __builtin_amdgcn_mfma_f32_32x32x16_f16(ah, qhB[ks], S1, 0, 0, 0);
        }
        __builtin_amdgcn_s_setprio(0);
    };
    // per-group softmax: updates (m_run,l_run,o2g), emits packed P fragments
    auto sm_one = [&](f32x16& S, float& m_run, float& l_run, f32x16 o2g[4],
                      f16x8& pb0, f16x8& pb1) {
        float m0 = fmaxf(fmaxf(S[0], S[1]), S[2]);
        float m1 = fmaxf(fmaxf(S[3], S[4]), S[5]);
        float m2 = fmaxf(fmaxf(S[6], S[7]), S[8]);
        float m3 = fmaxf(fmaxf(S[9], S[10]), S[11]);
        float m4 = fmaxf(fmaxf(S[12], S[13]), S[14]);
        float tm = fmaxf(fmaxf(fmaxf(m0, m1), m2), fmaxf(fmaxf(m3, m4), S[15]));
        tm = fmaxf(tm, __shfl_xor(tm, 32));

        if (__any(tm > m_run + 8.f)) {          // T13 defer-rescale
            const float Mn = fmaxf(m_run, tm);
            const float alpha = exp2f((m_run - Mn) * CL2);
            l_run *= alpha;
            #pragma unroll
            for (int gs = 0; gs < 4; ++gs)
                #pragma unroll
                for (int r = 0; r < 16; ++r) o2g[gs][r] *= alpha;
            m_run = Mn;
        }
        const float mc = m_run * CL2;
        float p[16];
        #pragma unroll
        for (int r = 0; r < 16; ++r) p[r] = exp2f(S[r] * CL2 - mc);
        float ts = (((p[0] + p[1]) + (p[2] + p[3])) + ((p[4] + p[5]) + (p[6] + p[7])))
                 + (((p[8] + p[9]) + (p[10] + p[11])) + ((p[12] + p[13]) + (p[14] + p[15])));
        l_run += ts;   // per-half partial; combined once in epilogue

        u32 pk[8];
        #pragma unroll
        for (int c = 0; c < 8; ++c) {
            auto r2 = __builtin_amdgcn_cvt_pkrtz(p[2 * c], p[2 * c + 1]);
            pk[c] = __builtin_bit_cast(u32, r2);
        }
        u32x4 t0, t1;
        t0.x = pk[0]; t0.y = pk[1]; t0.z = pk[2]; t0.w = pk[3];
        t1.x = pk[4]; t1.y = pk[5]; t1.z = pk[6]; t1.w = pk[7];
        pb0 = __builtin_bit_cast(f16x8, t0);
        pb1 = __builtin_bit_cast(f16x8, t1);
    };
    auto softmax_pv = [&](f32x16& SA, f32x16& SB, int buf) {
        f16x8 pa0, pa1, pb0, pb1;
        sm_one(SA, mA_run, lA_run, o2A, pa0, pa1);
        sm_one(SB, mB_run, lB_run, o2B, pb0, pb1);

        __builtin_amdgcn_s_setprio(1);
        #pragma unroll
        for (int gs = 0; gs < 4; ++gs) {
            const int g = gs * 32 + l31;
            const ushort_t* vrow = &vt[buf][g >> 1][(g & 1) * 32];
            f16x8 v0 = *reinterpret_cast<const f16x8*>(vrow + h5 * 8);
            f16x8 v1 = *reinterpret_cast<const f16x8*>(vrow + 16 + h5 * 8);
            o2A[gs] = __builtin_amdgcn_mfma_f32_32x32x16_f16(v0, pa0, o2A[gs], 0, 0, 0);
            o2A[gs] = __builtin_amdgcn_mfma_f32_32x32x16_f16(v1, pa1, o2A[gs], 0, 0, 0);
            o2B[gs] = __builtin_amdgcn_mfma_f32_32x32x16_f16(v0, pb0, o2B[gs], 0, 0, 0);
            o2B[gs] = __builtin_amdgcn_mfma_f32_32x32x16_f16(v1, pb1, o2B[gs], 0, 0, 0);
        }
        __builtin_amdgcn_s_setprio(0);
    };

    // prologue: stage tiles 0 and 1, compute scores(tile 0)
    stage_load(0); stage_write(0);
    stage_load(1); stage_write(1);
    __syncthreads();
    f32x16 SA0, SA1, SB0, SB1;
    scores(0, SA0, SA1);

    int cur = 0, nxt = 1, stg = 2;
    for (int mt = 0; mt < NT_ - 1; ++mt) {
        if (mt < NT_ - 2) stage_load(mt + 2);     // issue-early (T14)
        scores(nxt, SB0, SB1);                    // MFMA for next tile...
        if (mt < NT_ - 2) stage_write(stg);       // LDS write hidden under softmax
        softmax_pv(SA0, SA1, cur);                // ...overlaps softmax+PV of this one
        __syncthreads();
        SA0 = SB0; SA1 = SB1;
        const int tmp = cur; cur = nxt; nxt = stg; stg = tmp;
    }
    softmax_pv(SA0, SA1, cur);   // final tile (buffer 63 % 3 = 0)

    // epilogue: combine l halves, normalize, pack fp16, scatter-store out^T
    const float lA_tot = lA_run + __shfl_xor(lA_run, 32);
    const float lB_tot = lB_run + __shfl_xor(lB_run, 32);
    {
        const float inv = 1.f / lA_tot;
        ushort_t* dst = s_part + (ht * N_ + (size_t)(q0 + l31)) * F_;
        #pragma unroll
        for (int gs = 0; gs < 4; ++gs)
            #pragma unroll
            for (int rp = 0; rp < 8; ++rp) {
                const int r = rp * 2;
                const int g = gs * 32 + (r & 3) + 8 * (r >> 2) + 4 * h5;  // even
                auto r2 = __builtin_amdgcn_cvt_pkrtz(o2A[gs][r] * inv, o2A[gs][r + 1] * inv);
                *reinterpret_cast<u32*>(dst + g) = __builtin_bit_cast(u32, r2);
            }
    }
    {
        const float inv = 1.f / lB_tot;
        ushort_t* dst = s_part + (ht * N_ + (size_t)(q0 + 32 + l31)) * F_;
        #pragma unroll
        for (int gs = 0; gs < 4; ++gs)
            #pragma unroll
            for (int rp = 0; rp < 8; ++rp) {
                const int r = rp * 2;
                const int g = gs * 32 + (r & 3) + 8 * (r >> 2) + 4 * h5;  // even
                auto r2 = __builtin_amdgcn_cvt_pkrtz(o2B[gs][r] * inv, o2B[gs][r + 1] * inv);
                *reinterpret_cast<u32*>(dst + g) = __builtin_bit_cast(u32, r2);
            }
    }
}

// ---------------------------------------------------------------------------
// Kernel 3: out[n,g] = mean_h elu( (1/T) * sum_t s_part[h][t][n][g] ), fp16 in
// ---------------------------------------------------------------------------
__global__ __launch_bounds__(256) void k_out(const ushort_t* __restrict__ s_part,
                                             float* __restrict__ out) {
    const int idx = blockIdx.x * blockDim.x + threadIdx.x;
    if (idx >= (N_ * F_) / 4) return;
    const int n = idx >> 5;
    const int g0 = (idx & 31) * 4;
    const float invT = 1.f / (float)T_;

    float acc[4] = {0.f, 0.f, 0.f, 0.f};
    #pragma unroll
    for (int h = 0; h < H_; ++h) {
        float hs[4] = {0.f, 0.f, 0.f, 0.f};
        #pragma unroll
        for (int t = 0; t < T_; ++t) {
            const ushort_t* p = s_part + ((size_t)(h * T_ + t) * N_ + n) * F_ + g0;
            uint2 od = *reinterpret_cast<const uint2*>(p);
            hs[0] += (float)__builtin_bit_cast(_Float16, (ushort_t)(od.x & 0xffff));
            hs[1] += (float)__builtin_bit_cast(_Float16, (ushort_t)(od.x >> 16));
            hs[2] += (float)__builtin_bit_cast(_Float16, (ushort_t)(od.y & 0xffff));
            hs[3] += (float)__builtin_bit_cast(_Float16, (ushort_t)(od.y >> 16));
        }
        #pragma unroll
        for (int k = 0; k < 4; ++k) {
            const float e = hs[k] * invT;
            acc[k] += (e > 0.f) ? e : (expf(e) - 1.f);
        }
    }
    float4 r = {acc[0] * 0.25f, acc[1] * 0.25f, acc[2] * 0.25f, acc[3] * 0.25f};
    *reinterpret_cast<float4*>(out + (size_t)n * F_ + g0) = r;
}

extern "C" void kernel_launch(void* const* d_in, const int* in_sizes, int n_in,
                              void* d_out, int out_size, void* d_ws, size_t ws_size,
                              hipStream_t stream) {
    const float* x = (const float*)d_in[0];   // (T, N, F)
    const float* W = (const float*)d_in[1];   // (H, F, F)
    float* out = (float*)d_out;               // (N, F)

    // ws layout: th_hi 16MB | th_hiT 16MB | s_part(fp16) 16MB  (48MB)
    const size_t TH = (size_t)H_ * T_ * N_ * F_;        // 8,388,608
    ushort_t* th_hi  = (ushort_t*)d_ws;
    ushort_t* th_hiT = th_hi + TH;
    ushort_t* s_part = th_hiT + TH;

    k_th<<<H_ * T_ * (N_ / 64), 256, 0, stream>>>(x, W, th_hi, th_hiT);
    k_attn<<<512, 128, 0, stream>>>(th_hi, th_hiT, s_part);
    k_out<<<(N_ * F_ / 4 + 255) / 256, 256, 0, stream>>>(s_part, out);
}

// Round 10
// 152.665 us; speedup vs baseline: 1.3291x; 1.3291x over previous
//
#include <hip/hip_runtime.h>
#include <hip/hip_bf16.h>
#include <math.h>

#define T_ 8
#define N_ 2048
#define F_ 128
#define H_ 4
#define NT_ (N_ / 32)   // 64 key tiles per (h,t)

typedef unsigned int u32;
typedef unsigned short ushort_t;
typedef float f32x16 __attribute__((ext_vector_type(16)));
typedef _Float16 f16x8 __attribute__((ext_vector_type(8)));
typedef u32 u32x4 __attribute__((ext_vector_type(4)));

// ---------------------------------------------------------------------------
// Kernel 1: th = x @ W per (h,t) in fp32; writes fp16 hi and the transposed
// copy th_hiT[ht][n/32][g][32] with the inner m-index PERMUTED (bit2<->bit3)
// so PV's B-fragment needs no cross-lane shuffles. (unchanged from R8)
// ---------------------------------------------------------------------------
__global__ __launch_bounds__(256) void k_th(const float* __restrict__ x,
                                            const float* __restrict__ W,
                                            ushort_t* __restrict__ th_hi,
                                            ushort_t* __restrict__ th_hiT) {
    __shared__ float xs[64][132];

    const int b = blockIdx.x;
    const int h = b / (T_ * (N_ / 64));
    const int rem = b % (T_ * (N_ / 64));
    const int t = rem / (N_ / 64);
    const int n0 = (rem % (N_ / 64)) * 64;
    const int tid = threadIdx.x;

    {
        const int r = tid >> 2;
        const int c0 = (tid & 3) * 32;
        const float4* src = reinterpret_cast<const float4*>(
            x + ((size_t)t * N_ + (n0 + r)) * F_ + c0);
        #pragma unroll
        for (int u = 0; u < 8; ++u) {
            float4 v = src[u];
            int c = c0 + u * 4;
            xs[r][c + 0] = v.x; xs[r][c + 1] = v.y;
            xs[r][c + 2] = v.z; xs[r][c + 3] = v.w;
        }
    }
    __syncthreads();

    const int rowg = tid >> 4;
    const int colg = tid & 15;
    const int r0 = rowg * 4;
    const int c0 = colg * 8;

    float acc[4][8];
    #pragma unroll
    for (int i = 0; i < 4; ++i)
        #pragma unroll
        for (int j = 0; j < 8; ++j) acc[i][j] = 0.f;

    const float* Wb = W + (size_t)h * F_ * F_ + c0;
    #pragma unroll 4
    for (int f = 0; f < F_; ++f) {
        const float4 w0 = *reinterpret_cast<const float4*>(Wb + (size_t)f * F_);
        const float4 w1 = *reinterpret_cast<const float4*>(Wb + (size_t)f * F_ + 4);
        float a[4];
        #pragma unroll
        for (int i = 0; i < 4; ++i) a[i] = xs[r0 + i][f];
        #pragma unroll
        for (int i = 0; i < 4; ++i) {
            acc[i][0] += a[i] * w0.x; acc[i][1] += a[i] * w0.y;
            acc[i][2] += a[i] * w0.z; acc[i][3] += a[i] * w0.w;
            acc[i][4] += a[i] * w1.x; acc[i][5] += a[i] * w1.y;
            acc[i][6] += a[i] * w1.z; acc[i][7] += a[i] * w1.w;
        }
    }

    ushort_t hiv[4][8];
    #pragma unroll
    for (int i = 0; i < 4; ++i)
        #pragma unroll
        for (int j = 0; j < 8; ++j) {
            _Float16 hh = (_Float16)acc[i][j];   // RTN
            hiv[i][j] = __builtin_bit_cast(ushort_t, hh);
        }

    const size_t rowbase = (((size_t)h * T_ + t) * N_ + n0);
    #pragma unroll
    for (int i = 0; i < 4; ++i) {
        uint4 hv = *reinterpret_cast<uint4*>(&hiv[i][0]);
        *reinterpret_cast<uint4*>(th_hi + (rowbase + r0 + i) * F_ + c0) = hv;
    }

    // transposed chunked copy: [h][t][nc][g][32], inner m-index bit2<->bit3
    {
        const int nc = (n0 + r0) >> 5;
        const int nin = r0 & 31;                 // multiple of 4
        const int npin = (nin & 0x10) | ((nin & 4) << 1) | ((nin & 8) >> 1);
        ushort_t* base = th_hiT + ((((size_t)h * T_ + t) * (N_ / 32) + nc) * F_) * 32;
        #pragma unroll
        for (int j = 0; j < 8; ++j) {
            u32 p0 = (u32)hiv[0][j] | ((u32)hiv[1][j] << 16);
            u32 p1 = (u32)hiv[2][j] | ((u32)hiv[3][j] << 16);
            u32* dst = reinterpret_cast<u32*>(base + (size_t)(c0 + j) * 32 + npin);
            dst[0] = p0;
            dst[1] = p1;
        }
    }
}

// ---------------------------------------------------------------------------
// Kernel 2: MFMA flash attention, S^T = K*Q^T, single-term fp16 scores.
// R10 = R8 shape (4 waves x 32q, 2 blk/CU) + T15 PV-delay: PV of tile p-1
// issues right after scores of tile p+1 -> 32 contiguous MFMAs per iter;
// softmax(p) VALU overlaps the other wave's MFMA window. vt[4], kh[3].
// fp16 s_part output (proven R9 sub-win).
// ---------------------------------------------------------------------------
__global__ __launch_bounds__(256, 2) void k_attn(const ushort_t* __restrict__ th_hi,
                                                 const ushort_t* __restrict__ th_hiT,
                                                 ushort_t* __restrict__ s_part) {
    __shared__ ushort_t kh[3][32][128];
    __shared__ ushort_t vt[4][64][72];

    const int tid = threadIdx.x;
    const int lane = tid & 63;
    const int w = tid >> 6;
    const int l31 = lane & 31;
    const int h5 = lane >> 5;

    // XCD-grouping swizzle (proven: FETCH ~17MB): 64 vids per XCD
    const int vid = ((blockIdx.x & 7) << 6) | (blockIdx.x >> 3);
    const int h = vid >> 7;
    const int t = (vid >> 4) & 7;
    const int qt = vid & 15;
    const int q0 = qt * 128 + w * 32;

    const size_t ht = (size_t)h * T_ + t;
    const ushort_t* Khi_g = th_hi + ht * (N_ * F_);
    const ushort_t* VT_g  = th_hiT + ht * ((N_ / 32) * F_ * 32);
    const ushort_t* Qhi_g = th_hi + ((size_t)h * T_ + (T_ - 1)) * (N_ * F_);

    // Q fragments: lane -> q = q0+l31, f = ks*16 + h5*8 + j
    f16x8 qh[8];
    {
        const ushort_t* qrh = Qhi_g + (size_t)(q0 + l31) * F_ + h5 * 8;
        #pragma unroll
        for (int ks = 0; ks < 8; ++ks)
            qh[ks] = *reinterpret_cast<const f16x8*>(qrh + ks * 16);
    }

    const int sm = tid >> 3;            // K staging row 0..31
    const int sfc = tid & 7;            // K staging 16-elem f chunk
    const int ssx = sm & 15;
    const int sg = tid >> 1;            // V staging g-row 0..127
    const int smh = (tid & 1) * 16;     // V staging m half

    f32x16 o2[4];
    #pragma unroll
    for (int gs = 0; gs < 4; ++gs)
        #pragma unroll
        for (int r = 0; r < 16; ++r) o2[gs][r] = 0.f;

    float m_run = -3e38f, l_run = 0.f;  // l_run: per-half-wave PARTIAL
    const float CL2 = 1.4426950408889634f;

    uint4 sa0, sa1, sv0, sv1;   // T14 staging registers
    f16x8 pa0, pa1;             // T15 saved P fragments (previous tile)

    auto stage_load = [&](int mt) {
        const size_t grow = (size_t)(mt * 32 + sm) * F_ + sfc * 16;
        sa0 = *reinterpret_cast<const uint4*>(Khi_g + grow);
        sa1 = *reinterpret_cast<const uint4*>(Khi_g + grow + 8);
        const ushort_t* vsrc = VT_g + (size_t)mt * (F_ * 32) + (size_t)sg * 32 + smh;
        sv0 = *reinterpret_cast<const uint4*>(vsrc);
        sv1 = *reinterpret_cast<const uint4*>(vsrc + 8);
    };
    auto stage_write = [&](int kbuf, int vbuf) {
        *reinterpret_cast<uint4*>(&kh[kbuf][sm][((sfc * 2 + 0) ^ ssx) * 8]) = sa0;
        *reinterpret_cast<uint4*>(&kh[kbuf][sm][((sfc * 2 + 1) ^ ssx) * 8]) = sa1;
        ushort_t* vdst = &vt[vbuf][sg >> 1][(sg & 1) * 32 + smh];
        *reinterpret_cast<uint4*>(vdst) = sv0;
        *reinterpret_cast<uint4*>(vdst + 8) = sv1;
    };
    auto scores = [&](int kbuf) -> f32x16 {
        f32x16 S;
        #pragma unroll
        for (int r = 0; r < 16; ++r) S[r] = 0.f;
        __builtin_amdgcn_s_setprio(1);
        #pragma unroll
        for (int ks = 0; ks < 8; ++ks) {
            const f16x8 ah = *reinterpret_cast<const f16x8*>(
                &kh[kbuf][l31][((ks * 2 + h5) ^ (l31 & 15)) * 8]);
            S = __builtin_amdgcn_mfma_f32_32x32x16_f16(ah, qh[ks], S, 0, 0, 0);
        }
        __builtin_amdgcn_s_setprio(0);
        return S;
    };
    auto pv_apply = [&](int vbuf) {
        __builtin_amdgcn_s_setprio(1);
        #pragma unroll
        for (int gs = 0; gs < 4; ++gs) {
            const int g = gs * 32 + l31;
            const ushort_t* vrow = &vt[vbuf][g >> 1][(g & 1) * 32];
            f16x8 v0 = *reinterpret_cast<const f16x8*>(vrow + h5 * 8);
            f16x8 v1 = *reinterpret_cast<const f16x8*>(vrow + 16 + h5 * 8);
            o2[gs] = __builtin_amdgcn_mfma_f32_32x32x16_f16(v0, pa0, o2[gs], 0, 0, 0);
            o2[gs] = __builtin_amdgcn_mfma_f32_32x32x16_f16(v1, pa1, o2[gs], 0, 0, 0);
        }
        __builtin_amdgcn_s_setprio(0);
    };
    // softmax only: updates m_run/l_run, rescales o2 if needed, saves P frags
    auto sm_only = [&](f32x16& S) {
        float m0 = fmaxf(fmaxf(S[0], S[1]), S[2]);
        float m1 = fmaxf(fmaxf(S[3], S[4]), S[5]);
        float m2 = fmaxf(fmaxf(S[6], S[7]), S[8]);
        float m3 = fmaxf(fmaxf(S[9], S[10]), S[11]);
        float m4 = fmaxf(fmaxf(S[12], S[13]), S[14]);
        float tm = fmaxf(fmaxf(fmaxf(m0, m1), m2), fmaxf(fmaxf(m3, m4), S[15]));
        tm = fmaxf(tm, __shfl_xor(tm, 32));

        if (__any(tm > m_run + 8.f)) {          // T13 defer-rescale
            const float Mn = fmaxf(m_run, tm);
            const float alpha = exp2f((m_run - Mn) * CL2);
            l_run *= alpha;
            #pragma unroll
            for (int gs = 0; gs < 4; ++gs)
                #pragma unroll
                for (int r = 0; r < 16; ++r) o2[gs][r] *= alpha;
            m_run = Mn;
        }
        const float mc = m_run * CL2;
        float p[16];
        #pragma unroll
        for (int r = 0; r < 16; ++r) p[r] = exp2f(S[r] * CL2 - mc);
        float ts = (((p[0] + p[1]) + (p[2] + p[3])) + ((p[4] + p[5]) + (p[6] + p[7])))
                 + (((p[8] + p[9]) + (p[10] + p[11])) + ((p[12] + p[13]) + (p[14] + p[15])));
        l_run += ts;   // per-half partial; combined once in epilogue

        u32 pk[8];
        #pragma unroll
        for (int c = 0; c < 8; ++c) {
            auto r2 = __builtin_amdgcn_cvt_pkrtz(p[2 * c], p[2 * c + 1]);
            pk[c] = __builtin_bit_cast(u32, r2);
        }
        u32x4 t0, t1;
        t0.x = pk[0]; t0.y = pk[1]; t0.z = pk[2]; t0.w = pk[3];
        t1.x = pk[4]; t1.y = pk[5]; t1.z = pk[6]; t1.w = pk[7];
        pa0 = __builtin_bit_cast(f16x8, t0);
        pa1 = __builtin_bit_cast(f16x8, t1);
    };

    // prologue: stage tiles 0,1; scores(0)
    stage_load(0); stage_write(0, 0);
    stage_load(1); stage_write(1, 1);
    __syncthreads();
    f32x16 S_A = scores(0);

    // iter p=0: no PV yet
    stage_load(2);
    f32x16 S_B = scores(1);
    stage_write(2, 2);
    sm_only(S_A);            // tile 0 -> pa
    __syncthreads();
    S_A = S_B;

    // main loop p = 1 .. NT_-2: softmax(p), PV(p-1), scores(p+1), stage(p+2)
    for (int p = 1; p <= NT_ - 2; ++p) {
        const bool more = (p + 2 <= NT_ - 1);
        if (more) stage_load(p + 2);
        S_B = scores((p + 1) % 3);
        pv_apply((p - 1) & 3);                   // T15: PV of previous tile
        if (more) stage_write((p + 2) % 3, (p + 2) & 3);
        sm_only(S_A);                            // tile p -> pa
        __syncthreads();
        S_A = S_B;
    }

    // tail: PV(NT-2), softmax(NT-1), PV(NT-1)
    pv_apply((NT_ - 2) & 3);
    sm_only(S_A);            // tile NT-1 -> pa
    pv_apply((NT_ - 1) & 3);

    // epilogue: combine l halves, normalize, pack fp16, scatter-store out^T
    const float l_tot = l_run + __shfl_xor(l_run, 32);
    const float inv = 1.f / l_tot;
    ushort_t* dst = s_part + (ht * N_ + (size_t)(q0 + l31)) * F_;
    #pragma unroll
    for (int gs = 0; gs < 4; ++gs)
        #pragma unroll
        for (int rp = 0; rp < 8; ++rp) {
            const int r = rp * 2;
            const int g = gs * 32 + (r & 3) + 8 * (r >> 2) + 4 * h5;  // even
            auto r2 = __builtin_amdgcn_cvt_pkrtz(o2[gs][r] * inv, o2[gs][r + 1] * inv);
            *reinterpret_cast<u32*>(dst + g) = __builtin_bit_cast(u32, r2);
        }
}

// ---------------------------------------------------------------------------
// Kernel 3: out[n,g] = mean_h elu( (1/T) * sum_t s_part[h][t][n][g] ), fp16 in
// ---------------------------------------------------------------------------
__global__ __launch_bounds__(256) void k_out(const ushort_t* __restrict__ s_part,
                                             float* __restrict__ out) {
    const int idx = blockIdx.x * blockDim.x + threadIdx.x;
    if (idx >= (N_ * F_) / 4) return;
    const int n = idx >> 5;
    const int g0 = (idx & 31) * 4;
    const float invT = 1.f / (float)T_;

    float acc[4] = {0.f, 0.f, 0.f, 0.f};
    #pragma unroll
    for (int h = 0; h < H_; ++h) {
        float hs[4] = {0.f, 0.f, 0.f, 0.f};
        #pragma unroll
        for (int t = 0; t < T_; ++t) {
            const ushort_t* p = s_part + ((size_t)(h * T_ + t) * N_ + n) * F_ + g0;
            uint2 od = *reinterpret_cast<const uint2*>(p);
            hs[0] += (float)__builtin_bit_cast(_Float16, (ushort_t)(od.x & 0xffff));
            hs[1] += (float)__builtin_bit_cast(_Float16, (ushort_t)(od.x >> 16));
            hs[2] += (float)__builtin_bit_cast(_Float16, (ushort_t)(od.y & 0xffff));
            hs[3] += (float)__builtin_bit_cast(_Float16, (ushort_t)(od.y >> 16));
        }
        #pragma unroll
        for (int k = 0; k < 4; ++k) {
            const float e = hs[k] * invT;
            acc[k] += (e > 0.f) ? e : (expf(e) - 1.f);
        }
    }
    float4 r = {acc[0] * 0.25f, acc[1] * 0.25f, acc[2] * 0.25f, acc[3] * 0.25f};
    *reinterpret_cast<float4*>(out + (size_t)n * F_ + g0) = r;
}

extern "C" void kernel_launch(void* const* d_in, const int* in_sizes, int n_in,
                              void* d_out, int out_size, void* d_ws, size_t ws_size,
                              hipStream_t stream) {
    const float* x = (const float*)d_in[0];   // (T, N, F)
    const float* W = (const float*)d_in[1];   // (H, F, F)
    float* out = (float*)d_out;               // (N, F)

    // ws layout: th_hi 16MB | th_hiT 16MB | s_part(fp16) 16MB  (48MB)
    const size_t TH = (size_t)H_ * T_ * N_ * F_;        // 8,388,608
    ushort_t* th_hi  = (ushort_t*)d_ws;
    ushort_t* th_hiT = th_hi + TH;
    ushort_t* s_part = th_hiT + TH;

    k_th<<<H_ * T_ * (N_ / 64), 256, 0, stream>>>(x, W, th_hi, th_hiT);
    k_attn<<<512, 256, 0, stream>>>(th_hi, th_hiT, s_part);
    k_out<<<(N_ * F_ / 4 + 255) / 256, 256, 0, stream>>>(s_part, out);
}

// Round 11
// 119.979 us; speedup vs baseline: 1.6912x; 1.2724x over previous
//
#include <hip/hip_runtime.h>
#include <hip/hip_bf16.h>
#include <math.h>

#define T_ 8
#define N_ 2048
#define F_ 128
#define H_ 4
#define NT_ (N_ / 32)   // 64 key tiles per (h,t)

typedef unsigned int u32;
typedef unsigned short ushort_t;
typedef float f32x16 __attribute__((ext_vector_type(16)));
typedef _Float16 f16x8 __attribute__((ext_vector_type(8)));
typedef u32 u32x4 __attribute__((ext_vector_type(4)));

// ---------------------------------------------------------------------------
// Kernel 1 (R11): th = x @ W per (h,t) via fp16 MFMA, 2-term x split (x exact,
// W rounded to fp16 hi). No LDS, no barriers. 4 waves: (row-half, g-half).
// Writes th_hi[n][g] as packed u32 (lane owns adjacent col pair 2*l31+{0,1})
// and th_hiT[nc][g][32] with bit2<->bit3 n-permute (contiguous 16B runs).
// ---------------------------------------------------------------------------
__global__ __launch_bounds__(256) void k_th(const float* __restrict__ x,
                                            const float* __restrict__ W,
                                            ushort_t* __restrict__ th_hi,
                                            ushort_t* __restrict__ th_hiT) {
    const int b = blockIdx.x;
    const int h = b / (T_ * (N_ / 64));
    const int rem = b % (T_ * (N_ / 64));
    const int t = rem / (N_ / 64);
    const int n0 = (rem % (N_ / 64)) * 64;
    const int tid = threadIdx.x;
    const int lane = tid & 63;
    const int w = tid >> 6;
    const int l31 = lane & 31;
    const int h5 = lane >> 5;
    const int rh = w & 1;     // row half (32 rows)
    const int gh = w >> 1;    // g half (64 cols)

    // A fragments: x row = n0 + rh*32 + l31, k = ks*16 + h5*8 + j (fp16 hi+lo)
    f16x8 xh[8], xl[8];
    {
        const float* xrow = x + ((size_t)t * N_ + (n0 + rh * 32 + l31)) * F_ + h5 * 8;
        #pragma unroll
        for (int ks = 0; ks < 8; ++ks) {
            float4 v0 = *reinterpret_cast<const float4*>(xrow + ks * 16);
            float4 v1 = *reinterpret_cast<const float4*>(xrow + ks * 16 + 4);
            float vv[8] = {v0.x, v0.y, v0.z, v0.w, v1.x, v1.y, v1.z, v1.w};
            f16x8 hi, lo;
            #pragma unroll
            for (int j = 0; j < 8; ++j) {
                _Float16 hh = (_Float16)vv[j];
                hi[j] = hh;
                lo[j] = (_Float16)(vv[j] - (float)hh);
            }
            xh[ks] = hi; xl[ks] = lo;
        }
    }

    // B fragments: W col pair g = gh*64 + 2*l31 + {0,1}, k = ks*16 + h5*8 + j
    f16x8 wb0[8], wb1[8];
    {
        const float* Wb = W + (size_t)h * F_ * F_ + gh * 64 + 2 * l31;
        #pragma unroll
        for (int ks = 0; ks < 8; ++ks) {
            f16x8 b0, b1;
            #pragma unroll
            for (int j = 0; j < 8; ++j) {
                float2 wv = *reinterpret_cast<const float2*>(
                    Wb + (size_t)(ks * 16 + h5 * 8 + j) * F_);
                b0[j] = (_Float16)wv.x;
                b1[j] = (_Float16)wv.y;
            }
            wb0[ks] = b0; wb1[ks] = b1;
        }
    }

    f32x16 acc0, acc1;
    #pragma unroll
    for (int r = 0; r < 16; ++r) { acc0[r] = 0.f; acc1[r] = 0.f; }
    #pragma unroll
    for (int ks = 0; ks < 8; ++ks) {
        acc0 = __builtin_amdgcn_mfma_f32_32x32x16_f16(xh[ks], wb0[ks], acc0, 0, 0, 0);
        acc1 = __builtin_amdgcn_mfma_f32_32x32x16_f16(xh[ks], wb1[ks], acc1, 0, 0, 0);
        acc0 = __builtin_amdgcn_mfma_f32_32x32x16_f16(xl[ks], wb0[ks], acc0, 0, 0, 0);
        acc1 = __builtin_amdgcn_mfma_f32_32x32x16_f16(xl[ks], wb1[ks], acc1, 0, 0, 0);
    }

    const size_t ht = (size_t)h * T_ + t;

    // th_hi[n][g]: per reg, row r = (reg&3)+8*(reg>>2)+4*h5; packed col pair
    {
        ushort_t* base = th_hi + (ht * N_ + (size_t)(n0 + rh * 32)) * F_ + gh * 64 + 2 * l31;
        #pragma unroll
        for (int reg = 0; reg < 16; ++reg) {
            const int r = (reg & 3) + 8 * (reg >> 2) + 4 * h5;
            auto r2 = __builtin_amdgcn_cvt_pkrtz(acc0[reg], acc1[reg]);
            *reinterpret_cast<u32*>(base + (size_t)r * F_) = __builtin_bit_cast(u32, r2);
        }
    }

    // th_hiT[nc][g][32] with bit2<->3 permute: regs 0..7 -> npin 8*h5+0..7,
    // regs 8..15 -> npin 16+8*h5+0..7 (contiguous 16B runs, per g).
    {
        const int nc = (n0 >> 5) + rh;
        #pragma unroll
        for (int gs = 0; gs < 2; ++gs) {
            const int g = gh * 64 + 2 * l31 + gs;
            const f32x16& A = gs ? acc1 : acc0;
            ushort_t* bg = th_hiT + ((ht * (N_ / 32) + nc) * F_ + g) * 32;
            u32x4 run0, run1;
            run0.x = __builtin_bit_cast(u32, __builtin_amdgcn_cvt_pkrtz(A[0], A[1]));
            run0.y = __builtin_bit_cast(u32, __builtin_amdgcn_cvt_pkrtz(A[2], A[3]));
            run0.z = __builtin_bit_cast(u32, __builtin_amdgcn_cvt_pkrtz(A[4], A[5]));
            run0.w = __builtin_bit_cast(u32, __builtin_amdgcn_cvt_pkrtz(A[6], A[7]));
            run1.x = __builtin_bit_cast(u32, __builtin_amdgcn_cvt_pkrtz(A[8], A[9]));
            run1.y = __builtin_bit_cast(u32, __builtin_amdgcn_cvt_pkrtz(A[10], A[11]));
            run1.z = __builtin_bit_cast(u32, __builtin_amdgcn_cvt_pkrtz(A[12], A[13]));
            run1.w = __builtin_bit_cast(u32, __builtin_amdgcn_cvt_pkrtz(A[14], A[15]));
            *reinterpret_cast<u32x4*>(bg + 8 * h5) = run0;
            *reinterpret_cast<u32x4*>(bg + 16 + 8 * h5) = run1;
        }
    }
}

// ---------------------------------------------------------------------------
// Kernel 2: MFMA flash attention (R10 structure, proven 107us) + R11 micro:
// Q pre-scaled by log2(e) -> S in base-2 units, removes S*CL2 and m*CL2 muls.
// ---------------------------------------------------------------------------
__global__ __launch_bounds__(256, 2) void k_attn(const ushort_t* __restrict__ th_hi,
                                                 const ushort_t* __restrict__ th_hiT,
                                                 ushort_t* __restrict__ s_part) {
    __shared__ ushort_t kh[3][32][128];
    __shared__ ushort_t vt[4][64][72];

    const int tid = threadIdx.x;
    const int lane = tid & 63;
    const int w = tid >> 6;
    const int l31 = lane & 31;
    const int h5 = lane >> 5;

    // XCD-grouping swizzle (proven: FETCH ~17MB): 64 vids per XCD
    const int vid = ((blockIdx.x & 7) << 6) | (blockIdx.x >> 3);
    const int h = vid >> 7;
    const int t = (vid >> 4) & 7;
    const int qt = vid & 15;
    const int q0 = qt * 128 + w * 32;

    const size_t ht = (size_t)h * T_ + t;
    const ushort_t* Khi_g = th_hi + ht * (N_ * F_);
    const ushort_t* VT_g  = th_hiT + ht * ((N_ / 32) * F_ * 32);
    const ushort_t* Qhi_g = th_hi + ((size_t)h * T_ + (T_ - 1)) * (N_ * F_);

    // Q fragments, pre-scaled by log2(e) so scores arrive in base-2 units
    f16x8 qh[8];
    {
        const _Float16 L2E = (_Float16)1.4426950408889634f;
        const ushort_t* qrh = Qhi_g + (size_t)(q0 + l31) * F_ + h5 * 8;
        #pragma unroll
        for (int ks = 0; ks < 8; ++ks) {
            f16x8 qv = *reinterpret_cast<const f16x8*>(qrh + ks * 16);
            #pragma unroll
            for (int j = 0; j < 8; ++j) qv[j] *= L2E;
            qh[ks] = qv;
        }
    }

    const int sm = tid >> 3;            // K staging row 0..31
    const int sfc = tid & 7;            // K staging 16-elem f chunk
    const int ssx = sm & 15;
    const int sg = tid >> 1;            // V staging g-row 0..127
    const int smh = (tid & 1) * 16;     // V staging m half

    f32x16 o2[4];
    #pragma unroll
    for (int gs = 0; gs < 4; ++gs)
        #pragma unroll
        for (int r = 0; r < 16; ++r) o2[gs][r] = 0.f;

    float m_run = -3e38f, l_run = 0.f;  // base-2 units; l per-half partial

    uint4 sa0, sa1, sv0, sv1;   // T14 staging registers
    f16x8 pa0, pa1;             // T15 saved P fragments (previous tile)

    auto stage_load = [&](int mt) {
        const size_t grow = (size_t)(mt * 32 + sm) * F_ + sfc * 16;
        sa0 = *reinterpret_cast<const uint4*>(Khi_g + grow);
        sa1 = *reinterpret_cast<const uint4*>(Khi_g + grow + 8);
        const ushort_t* vsrc = VT_g + (size_t)mt * (F_ * 32) + (size_t)sg * 32 + smh;
        sv0 = *reinterpret_cast<const uint4*>(vsrc);
        sv1 = *reinterpret_cast<const uint4*>(vsrc + 8);
    };
    auto stage_write = [&](int kbuf, int vbuf) {
        *reinterpret_cast<uint4*>(&kh[kbuf][sm][((sfc * 2 + 0) ^ ssx) * 8]) = sa0;
        *reinterpret_cast<uint4*>(&kh[kbuf][sm][((sfc * 2 + 1) ^ ssx) * 8]) = sa1;
        ushort_t* vdst = &vt[vbuf][sg >> 1][(sg & 1) * 32 + smh];
        *reinterpret_cast<uint4*>(vdst) = sv0;
        *reinterpret_cast<uint4*>(vdst + 8) = sv1;
    };
    auto scores = [&](int kbuf) -> f32x16 {
        f32x16 S;
        #pragma unroll
        for (int r = 0; r < 16; ++r) S[r] = 0.f;
        __builtin_amdgcn_s_setprio(1);
        #pragma unroll
        for (int ks = 0; ks < 8; ++ks) {
            const f16x8 ah = *reinterpret_cast<const f16x8*>(
                &kh[kbuf][l31][((ks * 2 + h5) ^ (l31 & 15)) * 8]);
            S = __builtin_amdgcn_mfma_f32_32x32x16_f16(ah, qh[ks], S, 0, 0, 0);
        }
        __builtin_amdgcn_s_setprio(0);
        return S;
    };
    auto pv_apply = [&](int vbuf) {
        __builtin_amdgcn_s_setprio(1);
        #pragma unroll
        for (int gs = 0; gs < 4; ++gs) {
            const int g = gs * 32 + l31;
            const ushort_t* vrow = &vt[vbuf][g >> 1][(g & 1) * 32];
            f16x8 v0 = *reinterpret_cast<const f16x8*>(vrow + h5 * 8);
            f16x8 v1 = *reinterpret_cast<const f16x8*>(vrow + 16 + h5 * 8);
            o2[gs] = __builtin_amdgcn_mfma_f32_32x32x16_f16(v0, pa0, o2[gs], 0, 0, 0);
            o2[gs] = __builtin_amdgcn_mfma_f32_32x32x16_f16(v1, pa1, o2[gs], 0, 0, 0);
        }
        __builtin_amdgcn_s_setprio(0);
    };
    // softmax only (base-2): updates m/l, rescales o2 if needed, saves P frags
    auto sm_only = [&](f32x16& S) {
        float m0 = fmaxf(fmaxf(S[0], S[1]), S[2]);
        float m1 = fmaxf(fmaxf(S[3], S[4]), S[5]);
        float m2 = fmaxf(fmaxf(S[6], S[7]), S[8]);
        float m3 = fmaxf(fmaxf(S[9], S[10]), S[11]);
        float m4 = fmaxf(fmaxf(S[12], S[13]), S[14]);
        float tm = fmaxf(fmaxf(fmaxf(m0, m1), m2), fmaxf(fmaxf(m3, m4), S[15]));
        tm = fmaxf(tm, __shfl_xor(tm, 32));

        if (__any(tm > m_run + 11.5416f)) {     // T13 defer (e^8 bound, base-2)
            const float Mn = fmaxf(m_run, tm);
            const float alpha = exp2f(m_run - Mn);
            l_run *= alpha;
            #pragma unroll
            for (int gs = 0; gs < 4; ++gs)
                #pragma unroll
                for (int r = 0; r < 16; ++r) o2[gs][r] *= alpha;
            m_run = Mn;
        }
        float p[16];
        #pragma unroll
        for (int r = 0; r < 16; ++r) p[r] = exp2f(S[r] - m_run);
        float ts = (((p[0] + p[1]) + (p[2] + p[3])) + ((p[4] + p[5]) + (p[6] + p[7])))
                 + (((p[8] + p[9]) + (p[10] + p[11])) + ((p[12] + p[13]) + (p[14] + p[15])));
        l_run += ts;   // per-half partial; combined once in epilogue

        u32 pk[8];
        #pragma unroll
        for (int c = 0; c < 8; ++c) {
            auto r2 = __builtin_amdgcn_cvt_pkrtz(p[2 * c], p[2 * c + 1]);
            pk[c] = __builtin_bit_cast(u32, r2);
        }
        u32x4 t0, t1;
        t0.x = pk[0]; t0.y = pk[1]; t0.z = pk[2]; t0.w = pk[3];
        t1.x = pk[4]; t1.y = pk[5]; t1.z = pk[6]; t1.w = pk[7];
        pa0 = __builtin_bit_cast(f16x8, t0);
        pa1 = __builtin_bit_cast(f16x8, t1);
    };

    // prologue: stage tiles 0,1; scores(0)
    stage_load(0); stage_write(0, 0);
    stage_load(1); stage_write(1, 1);
    __syncthreads();
    f32x16 S_A = scores(0);

    // iter p=0: no PV yet
    stage_load(2);
    f32x16 S_B = scores(1);
    stage_write(2, 2);
    sm_only(S_A);            // tile 0 -> pa
    __syncthreads();
    S_A = S_B;

    // main loop p = 1 .. NT_-2: softmax(p), PV(p-1), scores(p+1), stage(p+2)
    for (int p = 1; p <= NT_ - 2; ++p) {
        const bool more = (p + 2 <= NT_ - 1);
        if (more) stage_load(p + 2);
        S_B = scores((p + 1) % 3);
        pv_apply((p - 1) & 3);                   // T15: PV of previous tile
        if (more) stage_write((p + 2) % 3, (p + 2) & 3);
        sm_only(S_A);                            // tile p -> pa
        __syncthreads();
        S_A = S_B;
    }

    // tail: PV(NT-2), softmax(NT-1), PV(NT-1)
    pv_apply((NT_ - 2) & 3);
    sm_only(S_A);            // tile NT-1 -> pa
    pv_apply((NT_ - 1) & 3);

    // epilogue: combine l halves, normalize, pack fp16, scatter-store out^T
    const float l_tot = l_run + __shfl_xor(l_run, 32);
    const float inv = 1.f / l_tot;
    ushort_t* dst = s_part + (ht * N_ + (size_t)(q0 + l31)) * F_;
    #pragma unroll
    for (int gs = 0; gs < 4; ++gs)
        #pragma unroll
        for (int rp = 0; rp < 8; ++rp) {
            const int r = rp * 2;
            const int g = gs * 32 + (r & 3) + 8 * (r >> 2) + 4 * h5;  // even
            auto r2 = __builtin_amdgcn_cvt_pkrtz(o2[gs][r] * inv, o2[gs][r + 1] * inv);
            *reinterpret_cast<u32*>(dst + g) = __builtin_bit_cast(u32, r2);
        }
}

// ---------------------------------------------------------------------------
// Kernel 3: out[n,g] = mean_h elu( (1/T) * sum_t s_part[h][t][n][g] ), fp16 in
// ---------------------------------------------------------------------------
__global__ __launch_bounds__(256) void k_out(const ushort_t* __restrict__ s_part,
                                             float* __restrict__ out) {
    const int idx = blockIdx.x * blockDim.x + threadIdx.x;
    if (idx >= (N_ * F_) / 4) return;
    const int n = idx >> 5;
    const int g0 = (idx & 31) * 4;
    const float invT = 1.f / (float)T_;

    float acc[4] = {0.f, 0.f, 0.f, 0.f};
    #pragma unroll
    for (int h = 0; h < H_; ++h) {
        float hs[4] = {0.f, 0.f, 0.f, 0.f};
        #pragma unroll
        for (int t = 0; t < T_; ++t) {
            const ushort_t* p = s_part + ((size_t)(h * T_ + t) * N_ + n) * F_ + g0;
            uint2 od = *reinterpret_cast<const uint2*>(p);
            hs[0] += (float)__builtin_bit_cast(_Float16, (ushort_t)(od.x & 0xffff));
            hs[1] += (float)__builtin_bit_cast(_Float16, (ushort_t)(od.x >> 16));
            hs[2] += (float)__builtin_bit_cast(_Float16, (ushort_t)(od.y & 0xffff));
            hs[3] += (float)__builtin_bit_cast(_Float16, (ushort_t)(od.y >> 16));
        }
        #pragma unroll
        for (int k = 0; k < 4; ++k) {
            const float e = hs[k] * invT;
            acc[k] += (e > 0.f) ? e : (expf(e) - 1.f);
        }
    }
    float4 r = {acc[0] * 0.25f, acc[1] * 0.25f, acc[2] * 0.25f, acc[3] * 0.25f};
    *reinterpret_cast<float4*>(out + (size_t)n * F_ + g0) = r;
}

extern "C" void kernel_launch(void* const* d_in, const int* in_sizes, int n_in,
                              void* d_out, int out_size, void* d_ws, size_t ws_size,
                              hipStream_t stream) {
    const float* x = (const float*)d_in[0];   // (T, N, F)
    const float* W = (const float*)d_in[1];   // (H, F, F)
    float* out = (float*)d_out;               // (N, F)

    // ws layout: th_hi 16MB | th_hiT 16MB | s_part(fp16) 16MB  (48MB)
    const size_t TH = (size_t)H_ * T_ * N_ * F_;        // 8,388,608
    ushort_t* th_hi  = (ushort_t*)d_ws;
    ushort_t* th_hiT = th_hi + TH;
    ushort_t* s_part = th_hiT + TH;

    k_th<<<H_ * T_ * (N_ / 64), 256, 0, stream>>>(x, W, th_hi, th_hiT);
    k_attn<<<512, 256, 0, stream>>>(th_hi, th_hiT, s_part);
    k_out<<<(N_ * F_ / 4 + 255) / 256, 256, 0, stream>>>(s_part, out);
}